// Round 15
// baseline (1961.342 us; speedup 1.0000x reference)
//
#include <hip/hip_runtime.h>

#define B_   64
#define T_   256
#define IN_  256
#define U_   768
#define C3_  2304
#define OUT_ 64
#define NWG  24
#define NTH  384
#define GRID 256           // claim grid: 1 WG/CU; 24 same-XCD WGs self-select

// ---- workspace map ----
#define ARR_OFF     0u
#define ARR_BYTES   0x20000u
#define CLAIM_OFF   0x18000u
#define RING_OFF    0x20000u
#define SLOT_STRIDE 98304u                      // [2 mt][48 kk][64 lane] x 16B
#define RING_BYTES  ((size_t)(T_ + 1) * SLOT_STRIDE)      // ~24.1 MB
#define XFRAG_OFF   0x1880000u
#define XFRAG_BYTES ((size_t)T_ * 2 * 16 * 1024)          // 8 MB
#define WS_NEED     ((size_t)XFRAG_OFF + XFRAG_BYTES)

// s_getreg imm for HW_REG_XCC_ID (id=20, offset=0, size=32) [verified m09]
#define XCC_GETREG_IMM ((31 << 11) | (0 << 6) | 20)

typedef __bf16 bf16x8 __attribute__((ext_vector_type(8)));
typedef float  f32x16 __attribute__((ext_vector_type(16)));
typedef int    i32x4  __attribute__((ext_vector_type(4)));

__device__ __forceinline__ unsigned short f2bf(float f) {   // RNE fp32->bf16
  unsigned u = __float_as_uint(f);
  u += 0x7fff + ((u >> 16) & 1);
  return (unsigned short)(u >> 16);
}
__device__ __forceinline__ unsigned pkbf(float lo, float hi) {
  unsigned r;
  asm volatile("v_cvt_pk_bf16_f32 %0, %1, %2" : "=v"(r) : "v"(lo), "v"(hi));
  return r;
}

#define PLAIN_LOAD(dst, src) \
  asm volatile("global_load_dwordx4 %0, %1, off" : "=v"(dst) : "v"(src))
#define PLAIN_STORE(dst, val) \
  asm volatile("global_store_dwordx4 %0, %1, off" :: "v"(dst), "v"(val) : "memory")
#define WAITV8 do { asm volatile("s_waitcnt vmcnt(8)" ::: "memory"); \
                    __builtin_amdgcn_sched_barrier(0); } while (0)
#define WAITV0 do { asm volatile("s_waitcnt vmcnt(0)" ::: "memory"); \
                    __builtin_amdgcn_sched_barrier(0); } while (0)

#define ISSUE8(BUF, KB) do { \
  _Pragma("unroll") \
  for (int i_ = 0; i_ < 8; ++i_) \
    PLAIN_LOAD(BUF[i_], pbase + ((KB) + i_) * 1024); \
} while (0)

// single accumulator chain (R12-validated codegen)
#define MFMA8(BUF, KB) do { \
  _Pragma("unroll") \
  for (int i_ = 0; i_ < 8; ++i_) { \
    bf16x8 av_ = wbase[((KB) + i_) * 64]; \
    accA = __builtin_amdgcn_mfma_f32_32x32x16_bf16( \
        av_, __builtin_bit_cast(bf16x8, BUF[i_]), accA, 0, 0, 0); \
  } \
} while (0)

// =====================================================================
// prep: x -> MFMA B-fragment-ordered bf16 frames (validated round 8/10)
// =====================================================================
__global__ void __launch_bounds__(256) prep_xfrag(
    const float* __restrict__ x, void* __restrict__ wsv)
{
  __shared__ float xls[64][264];
  const int t   = blockIdx.x;
  const int tid = threadIdx.x;
  const int l   = tid & 63;
  const int w   = tid >> 6;
  const int ln  = l & 31, lh = l >> 5;
  {
    const int row = tid >> 2, cb = (tid & 3) * 64;
    const float* src = x + (size_t)row * T_ * IN_ + (size_t)t * IN_ + cb;
    #pragma unroll
    for (int q = 0; q < 16; ++q)
      *(float4*)&xls[row][cb + q * 4] = *(const float4*)(src + q * 4);
  }
  __syncthreads();
  #pragma unroll
  for (int s = 0; s < 8; ++s) {
    const int idx = w * 8 + s, mt = idx >> 4, kk = idx & 15;
    const float* p = &xls[mt * 32 + ln][kk * 16 + lh * 8];
    union { bf16x8 v; unsigned u[4]; i32x4 q; } a;
    a.u[0] = pkbf(p[0], p[1]); a.u[1] = pkbf(p[2], p[3]);
    a.u[2] = pkbf(p[4], p[5]); a.u[3] = pkbf(p[6], p[7]);
    *(i32x4*)((char*)wsv + XFRAG_OFF
              + (size_t)((t * 2 + mt) * 16 + kk) * 1024 + (size_t)l * 16) = a.q;
  }
}

// =====================================================================
// main: R12 verbatim except per-producer flags (store+ballot, no atomic RMW)
// =====================================================================
__global__ void __launch_bounds__(NTH, 2) gru_mfma(
    const float* __restrict__ x, const float* __restrict__ kern,
    const float* __restrict__ rec, const float* __restrict__ bias,
    const float* __restrict__ w_out, const float* __restrict__ b_out,
    float* __restrict__ out, void* __restrict__ wsv)
{
  unsigned* arrive = (unsigned*)((char*)wsv + ARR_OFF);   // [(t*2+mt)*32 + wg]
  unsigned* claim  = (unsigned*)((char*)wsv + CLAIM_OFF); // [0..7]=per-XCD, [16]=winner
  char*     ring   = (char*)wsv + RING_OFF;

  __shared__ bf16x8  recF[3 * 48 * 64];     // A-frags (W^T) per gate, 144 KB
  __shared__ unsigned exch[2][2][64][9];    // z/r pre-acts bf16-packed, 9 KB
  __shared__ unsigned s_role;

  // ---- one-XCD claim (validated R12) ----
  if (threadIdx.x == 0) {
    unsigned xcc = __builtin_amdgcn_s_getreg(XCC_GETREG_IMM) & 7u;
    unsigned tk = __hip_atomic_fetch_add(&claim[xcc], 1u,
                                         __ATOMIC_RELAXED, __HIP_MEMORY_SCOPE_AGENT);
    if (tk == 23u) {                        // 24th arrival crowns this XCD
      unsigned exp = 0u;
      __hip_atomic_compare_exchange_strong(&claim[16], &exp, xcc + 1u,
          __ATOMIC_RELAXED, __ATOMIC_RELAXED, __HIP_MEMORY_SCOPE_AGENT);
    }
    unsigned w;
    while ((w = __hip_atomic_load(&claim[16], __ATOMIC_RELAXED,
                                  __HIP_MEMORY_SCOPE_AGENT)) == 0u)
      __builtin_amdgcn_s_sleep(2);
    s_role = (xcc == w - 1u && tk < 24u) ? tk : 0xFFFFFFFFu;
  }
  __syncthreads();
  const unsigned role = s_role;
  if (role == 0xFFFFFFFFu) return;          // not a worker

  const int tid = threadIdx.x;
  const int l   = tid & 63;
  const int j   = __builtin_amdgcn_readfirstlane(tid >> 6);  // wave 0..5
  const int mt  = j & 1;          // b-half: cols mt*32..+31
  const int g   = j >> 1;         // gate 0=z 1=r 2=h
  const int wg  = (int)role;      // logical WG id 0..23
  const int u0  = wg * 32;
  const int ln  = l & 31;
  const int lh  = l >> 5;
  const bool lo = (l < 32);
  const int wcol = g * U_ + u0 + ln;

  // ---- prologue: rec W^T A-frags -> LDS (mt halves split the kk range) ----
  for (int kk = mt * 24; kk < mt * 24 + 24; ++kk) {
    union { bf16x8 v; unsigned short s[8]; } fr;
    #pragma unroll
    for (int i = 0; i < 8; ++i)
      fr.s[i] = f2bf(rec[(size_t)(kk * 16 + lh * 8 + i) * C3_ + wcol]);
    recF[(g * 48 + kk) * 64 + l] = fr.v;
  }
  bf16x8 xkern[16];                       // kern A-frags in regs (64 VGPR)
  #pragma unroll
  for (int kk = 0; kk < 16; ++kk) {
    union { bf16x8 v; unsigned short s[8]; } fr;
    #pragma unroll
    for (int i = 0; i < 8; ++i)
      fr.s[i] = f2bf(kern[(size_t)(kk * 16 + lh * 8 + i) * C3_ + wcol]);
    xkern[kk] = fr.v;
  }

  f32x16 vbiasA, vbiasX;
  #pragma unroll
  for (int r = 0; r < 16; ++r) {
    int u = u0 + (r & 3) + 8 * (r >> 2) + 4 * lh;
    if (g < 2) { vbiasA[r] = bias[g * U_ + u] + bias[C3_ + g * U_ + u]; vbiasX[r] = 0.f; }
    else       { vbiasA[r] = bias[C3_ + 2 * U_ + u]; vbiasX[r] = bias[2 * U_ + u]; }
  }

  float hown[16];
  #pragma unroll
  for (int i = 0; i < 16; ++i) hown[i] = 0.f;

  const bf16x8* wbase = &recF[(g * 48) * 64 + l];
  const char*   xfrg  = (const char*)wsv + XFRAG_OFF + (size_t)l * 16;
  __syncthreads();

  for (int t = 0; t < T_; ++t) {
    f32x16 accA = vbiasA;
    f32x16 accX = vbiasX;

    // ---- x-projection from precomputed frags (fills poll shadow) ----
    {
      const char* xfb = xfrg + (size_t)((t * 2 + mt) * 16) * 1024;
      #pragma unroll
      for (int kk = 0; kk < 16; ++kk) {
        bf16x8 bv = *(const bf16x8*)(xfb + (size_t)kk * 1024);
        accX = __builtin_amdgcn_mfma_f32_32x32x16_bf16(xkern[kk], bv, accX, 0, 0, 0);
      }
    }

    // ---- wait h[t]: 24-lane flag-vector poll + ballot (no counter RMW) ----
    if (t > 0) {
      const unsigned* ap = arrive + ((size_t)t * 2 + mt) * 32 + (l < 24 ? l : 0);
      for (;;) {
        unsigned v = __hip_atomic_load(ap, __ATOMIC_RELAXED, __HIP_MEMORY_SCOPE_AGENT);
        if (__all((int)((l >= 24) | (v != 0u)))) break;
        __builtin_amdgcn_s_sleep(1);
      }
      WAITV0;

      const char* pbase = ring + (size_t)t * SLOT_STRIDE
                        + (size_t)mt * (48 * 1024) + (size_t)l * 16;
      i32x4 h0b[8], h1b[8];
      ISSUE8(h0b, 0);  ISSUE8(h1b, 8);
      WAITV8; MFMA8(h0b, 0);  ISSUE8(h0b, 16);
      WAITV8; MFMA8(h1b, 8);  ISSUE8(h1b, 24);
      WAITV8; MFMA8(h0b, 16); ISSUE8(h0b, 32);
      WAITV8; MFMA8(h1b, 24); ISSUE8(h1b, 40);
      WAITV8; MFMA8(h0b, 32);
      WAITV0; MFMA8(h1b, 40);
    }

    // ---- z/r publish packed pre-activations ----
    if (g < 2) {
      f32x16 pre = accA + accX;
      #pragma unroll
      for (int i = 0; i < 8; ++i)
        exch[mt][g][l][i] = pkbf(pre[2 * i], pre[2 * i + 1]);
    }
    __syncthreads();                       // sync1: exch written

    unsigned zw[8], rw[8];
    if (g == 2) {
      #pragma unroll
      for (int i = 0; i < 8; ++i) { zw[i] = exch[mt][0][l][i]; rw[i] = exch[mt][1][l][i]; }
    }
    __syncthreads();                       // sync2: exch free for next t

    if (g == 2) {
      f32x16 crec = accA;                  // recurrent part + b_rec_h
      float hn[16];
      #pragma unroll
      for (int i = 0; i < 8; ++i) {
        float zf[2] = { __uint_as_float(zw[i] << 16), __uint_as_float(zw[i] & 0xffff0000u) };
        float rf[2] = { __uint_as_float(rw[i] << 16), __uint_as_float(rw[i] & 0xffff0000u) };
        #pragma unroll
        for (int e = 0; e < 2; ++e) {
          const int r = 2 * i + e;
          float z  = 1.f / (1.f + __expf(-zf[e]));
          float rr = 1.f / (1.f + __expf(-rf[e]));
          float hh = fmaxf(0.f, accX[r] + rr * crec[r]);   // reset_after
          float h  = z * hown[r] + (1.f - z) * hh;
          hown[r] = h; hn[r] = h;
        }
      }
      // pack + cross-half exchange -> two B-frags (b = mt*32+ln)
      int w0 = (int)pkbf(hn[0],  hn[1]),  w1 = (int)pkbf(hn[2],  hn[3]);
      int w2 = (int)pkbf(hn[4],  hn[5]),  w3 = (int)pkbf(hn[6],  hn[7]);
      int w4 = (int)pkbf(hn[8],  hn[9]),  w5 = (int)pkbf(hn[10], hn[11]);
      int w6 = (int)pkbf(hn[12], hn[13]), w7 = (int)pkbf(hn[14], hn[15]);
      int sx0 = __shfl_xor(w0, 32, 64), sx1 = __shfl_xor(w1, 32, 64);
      int sx2 = __shfl_xor(w2, 32, 64), sx3 = __shfl_xor(w3, 32, 64);
      int sx4 = __shfl_xor(w4, 32, 64), sx5 = __shfl_xor(w5, 32, 64);
      int sx6 = __shfl_xor(w6, 32, 64), sx7 = __shfl_xor(w7, 32, 64);
      i32x4 f0, f1;
      f0[0] = lo ? w0 : sx2;  f0[1] = lo ? w1 : sx3;
      f0[2] = lo ? sx0 : w2;  f0[3] = lo ? sx1 : w3;
      f1[0] = lo ? w4 : sx6;  f1[1] = lo ? w5 : sx7;
      f1[2] = lo ? sx4 : w6;  f1[3] = lo ? sx5 : w7;

      char* dstb = ring + (size_t)(t + 1) * SLOT_STRIDE
                 + (size_t)(mt * 48 + 2 * wg) * 1024 + (size_t)l * 16;
      PLAIN_STORE(dstb, f0);               // write-through L1 -> XCD L2
      PLAIN_STORE(dstb + 1024, f1);
      asm volatile("s_waitcnt vmcnt(0)" ::: "memory");   // data at L2
      if (l == 0)                          // per-producer flag, no RMW
        __hip_atomic_store(arrive + ((size_t)(t + 1) * 2 + mt) * 32 + wg,
                           (unsigned)(t + 1),
                           __ATOMIC_RELAXED, __HIP_MEMORY_SCOPE_AGENT);
    }
  }

  // ---- dense tail: out = h[256] @ w_out + b_out (slot 256, L2) ----
  if (wg < 16) {
    const unsigned* a0 = arrive + ((size_t)T_ * 2 + 0) * 32 + (l < 24 ? l : 0);
    const unsigned* a1 = arrive + ((size_t)T_ * 2 + 1) * 32 + (l < 24 ? l : 0);
    for (;;) {
      unsigned v0 = __hip_atomic_load(a0, __ATOMIC_RELAXED, __HIP_MEMORY_SCOPE_AGENT);
      unsigned v1 = __hip_atomic_load(a1, __ATOMIC_RELAXED, __HIP_MEMORY_SCOPE_AGENT);
      if (__all((int)((l >= 24) | ((v0 != 0u) & (v1 != 0u))))) break;
      __builtin_amdgcn_s_sleep(2);
    }
    asm volatile("" ::: "memory");

    unsigned short* hrow = (unsigned short*)recF;   // reuse LDS: 4 rows x 768 bf16
    {
      const int blocal = tid / 96, c = tid % 96;
      const int kk = c >> 1, lhh = c & 1;
      const int b = wg * 4 + blocal, mtb = b >> 5, lnb = b & 31;
      const char* src = ring + (size_t)T_ * SLOT_STRIDE
                      + (size_t)(mtb * 48 + kk) * 1024 + (size_t)(lhh * 32 + lnb) * 16;
      i32x4 v;
      PLAIN_LOAD(v, src);
      asm volatile("s_waitcnt vmcnt(0)" ::: "memory");
      *(i32x4*)&hrow[blocal * 768 + kk * 16 + lhh * 8] = v;
    }
    __syncthreads();
    if (j < 4) {
      const int b = wg * 4 + j;
      float acc = 0.f;
      #pragma unroll 8
      for (int k = 0; k < U_; ++k)
        acc += __uint_as_float((unsigned)hrow[j * 768 + k] << 16)
             * w_out[(size_t)k * OUT_ + l];
      out[(size_t)b * OUT_ + l] = acc + b_out[l];
    }
  }
}

extern "C" void kernel_launch(void* const* d_in, const int* in_sizes, int n_in,
                              void* d_out, int out_size, void* d_ws, size_t ws_size,
                              hipStream_t stream) {
  const float* x     = (const float*)d_in[0];
  const float* kern  = (const float*)d_in[1];
  const float* rec   = (const float*)d_in[2];
  const float* bias  = (const float*)d_in[3];
  const float* w_out = (const float*)d_in[4];
  const float* b_out = (const float*)d_in[5];
  float* outp = (float*)d_out;
  void* wsv   = d_ws;

  if (ws_size < WS_NEED) return;

  hipMemsetAsync(d_ws, 0, ARR_BYTES, stream);    // flags + claim words
  prep_xfrag<<<T_, 256, 0, stream>>>(x, d_ws);

  void* args[] = {(void*)&x, (void*)&kern, (void*)&rec, (void*)&bias,
                  (void*)&w_out, (void*)&b_out, (void*)&outp, (void*)&wsv};
  hipLaunchCooperativeKernel(reinterpret_cast<void*>(&gru_mfma),
                             dim3(GRID), dim3(NTH), args, 0u, stream);
}

// Round 17
// 1959.122 us; speedup vs baseline: 1.0011x; 1.0011x over previous
//
#include <hip/hip_runtime.h>

#define B_   64
#define T_   256
#define IN_  256
#define U_   768
#define C3_  2304
#define OUT_ 64
#define NWG  24
#define NTH  384
#define GRID 256           // claim grid: 1 WG/CU; 24 same-XCD WGs self-select

// ---- workspace map (flags spread: one 128B line per producer per (t,mt)) ----
#define CLAIM_OFF   0u                          // claim[0..16] (one-time)
#define ARR_OFF     0x1000u
// flag dword index: ((t*2+mt)*24 + wg) * 32   (128B stride per flag)
#define RING_OFF    0x200000u
#define SLOT_STRIDE 98304u                      // [2 mt][48 kk][64 lane] x 16B
#define RING_BYTES  ((size_t)(T_ + 1) * SLOT_STRIDE)      // ~24.1 MB
#define XFRAG_OFF   0x1B00000u
#define XFRAG_BYTES ((size_t)T_ * 2 * 16 * 1024)          // 8 MB
#define WS_NEED     ((size_t)XFRAG_OFF + XFRAG_BYTES)     // ~36.7 MB
#define ZERO_BYTES  0x200000u                   // claim + flag region

// s_getreg imm for HW_REG_XCC_ID (id=20, offset=0, size=32) [verified m09]
#define XCC_GETREG_IMM ((31 << 11) | (0 << 6) | 20)

typedef __bf16 bf16x8 __attribute__((ext_vector_type(8)));
typedef float  f32x16 __attribute__((ext_vector_type(16)));
typedef int    i32x4  __attribute__((ext_vector_type(4)));

__device__ __forceinline__ unsigned short f2bf(float f) {   // RNE fp32->bf16
  unsigned u = __float_as_uint(f);
  u += 0x7fff + ((u >> 16) & 1);
  return (unsigned short)(u >> 16);
}
__device__ __forceinline__ unsigned pkbf(float lo, float hi) {
  unsigned r;
  asm volatile("v_cvt_pk_bf16_f32 %0, %1, %2" : "=v"(r) : "v"(lo), "v"(hi));
  return r;
}

#define PLAIN_LOAD(dst, src) \
  asm volatile("global_load_dwordx4 %0, %1, off" : "=v"(dst) : "v"(src))
#define PLAIN_STORE(dst, val) \
  asm volatile("global_store_dwordx4 %0, %1, off" :: "v"(dst), "v"(val) : "memory")
#define WAITV8 do { asm volatile("s_waitcnt vmcnt(8)" ::: "memory"); \
                    __builtin_amdgcn_sched_barrier(0); } while (0)
#define WAITV0 do { asm volatile("s_waitcnt vmcnt(0)" ::: "memory"); \
                    __builtin_amdgcn_sched_barrier(0); } while (0)

#define ISSUE8(BUF, KB) do { \
  _Pragma("unroll") \
  for (int i_ = 0; i_ < 8; ++i_) \
    PLAIN_LOAD(BUF[i_], pbase + ((KB) + i_) * 1024); \
} while (0)

// single accumulator chain (R12/R15-validated codegen)
#define MFMA8(BUF, KB) do { \
  _Pragma("unroll") \
  for (int i_ = 0; i_ < 8; ++i_) { \
    bf16x8 av_ = wbase[((KB) + i_) * 64]; \
    accA = __builtin_amdgcn_mfma_f32_32x32x16_bf16( \
        av_, __builtin_bit_cast(bf16x8, BUF[i_]), accA, 0, 0, 0); \
  } \
} while (0)

// =====================================================================
// prep: x -> MFMA B-fragment-ordered bf16 frames (validated round 8/10)
// =====================================================================
__global__ void __launch_bounds__(256) prep_xfrag(
    const float* __restrict__ x, void* __restrict__ wsv)
{
  __shared__ float xls[64][264];
  const int t   = blockIdx.x;
  const int tid = threadIdx.x;
  const int l   = tid & 63;
  const int w   = tid >> 6;
  const int ln  = l & 31, lh = l >> 5;
  {
    const int row = tid >> 2, cb = (tid & 3) * 64;
    const float* src = x + (size_t)row * T_ * IN_ + (size_t)t * IN_ + cb;
    #pragma unroll
    for (int q = 0; q < 16; ++q)
      *(float4*)&xls[row][cb + q * 4] = *(const float4*)(src + q * 4);
  }
  __syncthreads();
  #pragma unroll
  for (int s = 0; s < 8; ++s) {
    const int idx = w * 8 + s, mt = idx >> 4, kk = idx & 15;
    const float* p = &xls[mt * 32 + ln][kk * 16 + lh * 8];
    union { bf16x8 v; unsigned u[4]; i32x4 q; } a;
    a.u[0] = pkbf(p[0], p[1]); a.u[1] = pkbf(p[2], p[3]);
    a.u[2] = pkbf(p[4], p[5]); a.u[3] = pkbf(p[6], p[7]);
    *(i32x4*)((char*)wsv + XFRAG_OFF
              + (size_t)((t * 2 + mt) * 16 + kk) * 1024 + (size_t)l * 16) = a.q;
  }
}

// =====================================================================
// main: R15 verbatim except flags spread to one 128B line per producer
// =====================================================================
__global__ void __launch_bounds__(NTH, 2) gru_mfma(
    const float* __restrict__ x, const float* __restrict__ kern,
    const float* __restrict__ rec, const float* __restrict__ bias,
    const float* __restrict__ w_out, const float* __restrict__ b_out,
    float* __restrict__ out, void* __restrict__ wsv)
{
  unsigned* arrive = (unsigned*)((char*)wsv + ARR_OFF);   // [((t*2+mt)*24+wg)*32]
  unsigned* claim  = (unsigned*)((char*)wsv + CLAIM_OFF); // [0..7]=per-XCD, [16]=winner
  char*     ring   = (char*)wsv + RING_OFF;

  __shared__ bf16x8  recF[3 * 48 * 64];     // A-frags (W^T) per gate, 144 KB
  __shared__ unsigned exch[2][2][64][9];    // z/r pre-acts bf16-packed, 9 KB
  __shared__ unsigned s_role;

  // ---- one-XCD claim (validated R12/R15) ----
  if (threadIdx.x == 0) {
    unsigned xcc = __builtin_amdgcn_s_getreg(XCC_GETREG_IMM) & 7u;
    unsigned tk = __hip_atomic_fetch_add(&claim[xcc], 1u,
                                         __ATOMIC_RELAXED, __HIP_MEMORY_SCOPE_AGENT);
    if (tk == 23u) {                        // 24th arrival crowns this XCD
      unsigned exp = 0u;
      __hip_atomic_compare_exchange_strong(&claim[16], &exp, xcc + 1u,
          __ATOMIC_RELAXED, __ATOMIC_RELAXED, __HIP_MEMORY_SCOPE_AGENT);
    }
    unsigned w;
    while ((w = __hip_atomic_load(&claim[16], __ATOMIC_RELAXED,
                                  __HIP_MEMORY_SCOPE_AGENT)) == 0u)
      __builtin_amdgcn_s_sleep(2);
    s_role = (xcc == w - 1u && tk < 24u) ? tk : 0xFFFFFFFFu;
  }
  __syncthreads();
  const unsigned role = s_role;
  if (role == 0xFFFFFFFFu) return;          // not a worker

  const int tid = threadIdx.x;
  const int l   = tid & 63;
  const int j   = __builtin_amdgcn_readfirstlane(tid >> 6);  // wave 0..5
  const int mt  = j & 1;          // b-half: cols mt*32..+31
  const int g   = j >> 1;         // gate 0=z 1=r 2=h
  const int wg  = (int)role;      // logical WG id 0..23
  const int u0  = wg * 32;
  const int ln  = l & 31;
  const int lh  = l >> 5;
  const bool lo = (l < 32);
  const int wcol = g * U_ + u0 + ln;

  // ---- prologue: rec W^T A-frags -> LDS (mt halves split the kk range) ----
  for (int kk = mt * 24; kk < mt * 24 + 24; ++kk) {
    union { bf16x8 v; unsigned short s[8]; } fr;
    #pragma unroll
    for (int i = 0; i < 8; ++i)
      fr.s[i] = f2bf(rec[(size_t)(kk * 16 + lh * 8 + i) * C3_ + wcol]);
    recF[(g * 48 + kk) * 64 + l] = fr.v;
  }
  bf16x8 xkern[16];                       // kern A-frags in regs (64 VGPR)
  #pragma unroll
  for (int kk = 0; kk < 16; ++kk) {
    union { bf16x8 v; unsigned short s[8]; } fr;
    #pragma unroll
    for (int i = 0; i < 8; ++i)
      fr.s[i] = f2bf(kern[(size_t)(kk * 16 + lh * 8 + i) * C3_ + wcol]);
    xkern[kk] = fr.v;
  }

  f32x16 vbiasA, vbiasX;
  #pragma unroll
  for (int r = 0; r < 16; ++r) {
    int u = u0 + (r & 3) + 8 * (r >> 2) + 4 * lh;
    if (g < 2) { vbiasA[r] = bias[g * U_ + u] + bias[C3_ + g * U_ + u]; vbiasX[r] = 0.f; }
    else       { vbiasA[r] = bias[C3_ + 2 * U_ + u]; vbiasX[r] = bias[2 * U_ + u]; }
  }

  float hown[16];
  #pragma unroll
  for (int i = 0; i < 16; ++i) hown[i] = 0.f;

  const bf16x8* wbase = &recF[(g * 48) * 64 + l];
  const char*   xfrg  = (const char*)wsv + XFRAG_OFF + (size_t)l * 16;
  __syncthreads();

  for (int t = 0; t < T_; ++t) {
    f32x16 accA = vbiasA;
    f32x16 accX = vbiasX;

    // ---- x-projection from precomputed frags (fills poll shadow) ----
    {
      const char* xfb = xfrg + (size_t)((t * 2 + mt) * 16) * 1024;
      #pragma unroll
      for (int kk = 0; kk < 16; ++kk) {
        bf16x8 bv = *(const bf16x8*)(xfb + (size_t)kk * 1024);
        accX = __builtin_amdgcn_mfma_f32_32x32x16_bf16(xkern[kk], bv, accX, 0, 0, 0);
      }
    }

    // ---- wait h[t]: 24-lane poll, one 128B line per producer ----
    if (t > 0) {
      const unsigned* ap = arrive + ((size_t)t * 2 + mt) * (24 * 32)
                         + (size_t)(l < 24 ? l : 0) * 32;
      for (;;) {
        unsigned v = __hip_atomic_load(ap, __ATOMIC_RELAXED, __HIP_MEMORY_SCOPE_AGENT);
        if (__all((int)((l >= 24) | (v != 0u)))) break;
        __builtin_amdgcn_s_sleep(1);
      }
      WAITV0;

      const char* pbase = ring + (size_t)t * SLOT_STRIDE
                        + (size_t)mt * (48 * 1024) + (size_t)l * 16;
      i32x4 h0b[8], h1b[8];
      ISSUE8(h0b, 0);  ISSUE8(h1b, 8);
      WAITV8; MFMA8(h0b, 0);  ISSUE8(h0b, 16);
      WAITV8; MFMA8(h1b, 8);  ISSUE8(h1b, 24);
      WAITV8; MFMA8(h0b, 16); ISSUE8(h0b, 32);
      WAITV8; MFMA8(h1b, 24); ISSUE8(h1b, 40);
      WAITV8; MFMA8(h0b, 32);
      WAITV0; MFMA8(h1b, 40);
    }

    // ---- z/r publish packed pre-activations ----
    if (g < 2) {
      f32x16 pre = accA + accX;
      #pragma unroll
      for (int i = 0; i < 8; ++i)
        exch[mt][g][l][i] = pkbf(pre[2 * i], pre[2 * i + 1]);
    }
    __syncthreads();                       // sync1: exch written

    unsigned zw[8], rw[8];
    if (g == 2) {
      #pragma unroll
      for (int i = 0; i < 8; ++i) { zw[i] = exch[mt][0][l][i]; rw[i] = exch[mt][1][l][i]; }
    }
    __syncthreads();                       // sync2: exch free for next t

    if (g == 2) {
      f32x16 crec = accA;                  // recurrent part + b_rec_h
      float hn[16];
      #pragma unroll
      for (int i = 0; i < 8; ++i) {
        float zf[2] = { __uint_as_float(zw[i] << 16), __uint_as_float(zw[i] & 0xffff0000u) };
        float rf[2] = { __uint_as_float(rw[i] << 16), __uint_as_float(rw[i] & 0xffff0000u) };
        #pragma unroll
        for (int e = 0; e < 2; ++e) {
          const int r = 2 * i + e;
          float z  = 1.f / (1.f + __expf(-zf[e]));
          float rr = 1.f / (1.f + __expf(-rf[e]));
          float hh = fmaxf(0.f, accX[r] + rr * crec[r]);   // reset_after
          float h  = z * hown[r] + (1.f - z) * hh;
          hown[r] = h; hn[r] = h;
        }
      }
      // pack + cross-half exchange -> two B-frags (b = mt*32+ln)
      int w0 = (int)pkbf(hn[0],  hn[1]),  w1 = (int)pkbf(hn[2],  hn[3]);
      int w2 = (int)pkbf(hn[4],  hn[5]),  w3 = (int)pkbf(hn[6],  hn[7]);
      int w4 = (int)pkbf(hn[8],  hn[9]),  w5 = (int)pkbf(hn[10], hn[11]);
      int w6 = (int)pkbf(hn[12], hn[13]), w7 = (int)pkbf(hn[14], hn[15]);
      int sx0 = __shfl_xor(w0, 32, 64), sx1 = __shfl_xor(w1, 32, 64);
      int sx2 = __shfl_xor(w2, 32, 64), sx3 = __shfl_xor(w3, 32, 64);
      int sx4 = __shfl_xor(w4, 32, 64), sx5 = __shfl_xor(w5, 32, 64);
      int sx6 = __shfl_xor(w6, 32, 64), sx7 = __shfl_xor(w7, 32, 64);
      i32x4 f0, f1;
      f0[0] = lo ? w0 : sx2;  f0[1] = lo ? w1 : sx3;
      f0[2] = lo ? sx0 : w2;  f0[3] = lo ? sx1 : w3;
      f1[0] = lo ? w4 : sx6;  f1[1] = lo ? w5 : sx7;
      f1[2] = lo ? sx4 : w6;  f1[3] = lo ? sx5 : w7;

      char* dstb = ring + (size_t)(t + 1) * SLOT_STRIDE
                 + (size_t)(mt * 48 + 2 * wg) * 1024 + (size_t)l * 16;
      PLAIN_STORE(dstb, f0);               // write-through L1 -> XCD L2
      PLAIN_STORE(dstb + 1024, f1);
      asm volatile("s_waitcnt vmcnt(0)" ::: "memory");   // data at L2
      if (l == 0)                          // private flag line, no RMW
        __hip_atomic_store(arrive + ((size_t)(t + 1) * 2 + mt) * (24 * 32)
                                   + (size_t)wg * 32,
                           (unsigned)(t + 1),
                           __ATOMIC_RELAXED, __HIP_MEMORY_SCOPE_AGENT);
    }
  }

  // ---- dense tail: out = h[256] @ w_out + b_out (slot 256, L2) ----
  if (wg < 16) {
    const unsigned* a0 = arrive + ((size_t)T_ * 2 + 0) * (24 * 32)
                       + (size_t)(l < 24 ? l : 0) * 32;
    const unsigned* a1 = arrive + ((size_t)T_ * 2 + 1) * (24 * 32)
                       + (size_t)(l < 24 ? l : 0) * 32;
    for (;;) {
      unsigned v0 = __hip_atomic_load(a0, __ATOMIC_RELAXED, __HIP_MEMORY_SCOPE_AGENT);
      unsigned v1 = __hip_atomic_load(a1, __ATOMIC_RELAXED, __HIP_MEMORY_SCOPE_AGENT);
      if (__all((int)((l >= 24) | ((v0 != 0u) & (v1 != 0u))))) break;
      __builtin_amdgcn_s_sleep(2);
    }
    asm volatile("" ::: "memory");

    unsigned short* hrow = (unsigned short*)recF;   // reuse LDS: 4 rows x 768 bf16
    {
      const int blocal = tid / 96, c = tid % 96;
      const int kk = c >> 1, lhh = c & 1;
      const int b = wg * 4 + blocal, mtb = b >> 5, lnb = b & 31;
      const char* src = ring + (size_t)T_ * SLOT_STRIDE
                      + (size_t)(mtb * 48 + kk) * 1024 + (size_t)(lhh * 32 + lnb) * 16;
      i32x4 v;
      PLAIN_LOAD(v, src);
      asm volatile("s_waitcnt vmcnt(0)" ::: "memory");
      *(i32x4*)&hrow[blocal * 768 + kk * 16 + lhh * 8] = v;
    }
    __syncthreads();
    if (j < 4) {
      const int b = wg * 4 + j;
      float acc = 0.f;
      #pragma unroll 8
      for (int k = 0; k < U_; ++k)
        acc += __uint_as_float((unsigned)hrow[j * 768 + k] << 16)
             * w_out[(size_t)k * OUT_ + l];
      out[(size_t)b * OUT_ + l] = acc + b_out[l];
    }
  }
}

extern "C" void kernel_launch(void* const* d_in, const int* in_sizes, int n_in,
                              void* d_out, int out_size, void* d_ws, size_t ws_size,
                              hipStream_t stream) {
  const float* x     = (const float*)d_in[0];
  const float* kern  = (const float*)d_in[1];
  const float* rec   = (const float*)d_in[2];
  const float* bias  = (const float*)d_in[3];
  const float* w_out = (const float*)d_in[4];
  const float* b_out = (const float*)d_in[5];
  float* outp = (float*)d_out;
  void* wsv   = d_ws;

  if (ws_size < WS_NEED) return;

  hipMemsetAsync(d_ws, 0, ZERO_BYTES, stream);   // claim + spread flag region
  prep_xfrag<<<T_, 256, 0, stream>>>(x, d_ws);

  void* args[] = {(void*)&x, (void*)&kern, (void*)&rec, (void*)&bias,
                  (void*)&w_out, (void*)&b_out, (void*)&outp, (void*)&wsv};
  hipLaunchCooperativeKernel(reinterpret_cast<void*>(&gru_mfma),
                             dim3(GRID), dim3(NTH), args, 0u, stream);
}